// Round 1
// baseline (1049.128 us; speedup 1.0000x reference)
//
#include <hip/hip_runtime.h>
#include <stdint.h>

typedef __attribute__((ext_vector_type(8))) short short8;
typedef __attribute__((ext_vector_type(4))) float floatx4;

#define MFMA16(a, b, c) __builtin_amdgcn_mfma_f32_16x16x32_bf16(a, b, c, 0, 0, 0)

// Pack two fp32 -> bf16 pair (lo, hi) in ONE v_perm_b32 after +0x8000
// round-half-up (vs software RNE: ~10 VALU -> 3 VALU per pair).
__device__ __forceinline__ unsigned pkbf(float lo, float hi) {
    const unsigned a = __builtin_bit_cast(unsigned, lo) + 0x8000u;
    const unsigned b = __builtin_bit_cast(unsigned, hi) + 0x8000u;
    return __builtin_amdgcn_perm(b, a, 0x07060302u);  // {b.hi16, a.hi16}
}
__device__ __forceinline__ unsigned short f2bf(float x) {
    unsigned u = __builtin_bit_cast(unsigned, x);
    u = (u + 0x7fffu + ((u >> 16) & 1u)) >> 16;  // RNE (cold paths only)
    return (unsigned short)u;
}

// Activation tiles are 32x128 bf16 viewed as u32 pairs: u32 index u of a row
// holds bf16 cols (2u, 2u+1). 16B chunks XOR-swizzled by row&15: b32 C-layout
// writes stay <=2-way (free), b128 A-frag reads are bank-balanced.
__device__ __forceinline__ int hphys(int row, int u) {
    return row * 64 + ((((u >> 2) ^ (row & 15)) << 2) | (u & 3));
}

// == R14: occupancy release. R1-R13 established VGPR=64 (8-wave budget) but
// LDS 38400 capped residency at 4 WGs/CU (39.6% occ, MfmaUtil 20 /
// VALUBusy 42 -> barrier/latency-bound; wave scaling 2->3->4 was
// 287->220->205 us). This round: LDS -> 19968 B so 8 WGs/CU (32 waves/CU):
//  * 1 batch per WG (grid 4096): accT 4 KB -> 2 KB, no bl-split.
//  * 32-row tiles: h1+h2 = 16 KB (hphys / row&15==c folds unchanged).
//  * W2 B-frag image staged in two 16 KB col-halves into sbuf (same R6
//    rot-map, B -= 16*half remap); waves 0,1 read frags after half 0,
//    waves 2,3 after half 1.
//  * Layer 3 k-split: wave w = row-half (w>>1) x k-half (w&1), 2 MFMAs,
//    bias only on (w&1)==0; 2-way ds_add resolves the k-sum.
// N-split: wave w owns hidden cols [32w,32w+32) for layers 1-2 (W1/W2 B-frags
// in regs; even/odd col pairing -> packed b32 LDS writes). sw==c identity
// folds the A-frag swizzle to base ^ (k<<2).
__global__ __launch_bounds__(256)
__attribute__((amdgpu_waves_per_eu(8, 8)))
void NeuralNet_37615323578557_kernel(
        const float* __restrict__ x, const float* __restrict__ t,
        const float* __restrict__ fW1, const float* __restrict__ fb1,
        const float* __restrict__ fW2, const float* __restrict__ fb2,
        const float* __restrict__ fW3, const float* __restrict__ fb3,
        const float* __restrict__ gW1, const float* __restrict__ gb1,
        const float* __restrict__ gW2, const float* __restrict__ gb2,
        const float* __restrict__ gW3, const float* __restrict__ gb3,
        const float* __restrict__ iW1, const float* __restrict__ ib1,
        const float* __restrict__ iW2, const float* __restrict__ ib2,
        const float* __restrict__ iW3, const float* __restrict__ ib3,
        float* __restrict__ out) {
    __shared__ unsigned sbuf[4096];             // 16 KB: W2 half-image / h1|h2
    __shared__ unsigned short fbuf[64 * 8];     // 1 KB feats (2 tiles) / init
    __shared__ float accT[256 * 2];             // 2 KB output accumulator
    __shared__ unsigned short w3img[256];       // 512 B W3 B-frag image

    unsigned* const h1buf = sbuf;               // 8 KB (32 rows x 64 u32)
    unsigned* const h2buf = sbuf + 2048;        // 8 KB

    const int tid  = threadIdx.x;
    const int lane = tid & 63;
    const int w    = tid >> 6;      // wave 0..3
    const int c    = lane & 15;     // MFMA low index (m for A, n for B/C)
    const int q    = lane >> 4;     // MFMA quad
    const int b0   = blockIdx.x;    // ONE batch per WG

    // ---- zero the output accumulator ----
    accT[tid] = 0.0f;
    accT[tid + 256] = 0.0f;
    __syncthreads();

    // ---- init MLP: wave 0, pure fp32 VALU; scratch = fbuf ----
    if (w == 0) {
        float* h1s = (float*)fbuf;
        const float* xb = x + (size_t)b0 * 514;
        const float f0 = xb[0], f1 = xb[1], f2 = t[b0];
        const int u0 = lane, u1 = lane + 64;
        const float h0 = fmaxf(iW1[u0] * f0 + iW1[128 + u0] * f1 + iW1[256 + u0] * f2 + ib1[u0], 0.f);
        const float h1 = fmaxf(iW1[u1] * f0 + iW1[128 + u1] * f1 + iW1[256 + u1] * f2 + ib1[u1], 0.f);
        h1s[u0] = h0;
        h1s[u1] = h1;
        float a0 = ib2[lane], a1 = ib2[lane + 64];
        for (int k = 0; k < 128; ++k) {
            const float hv = h1s[k];
            a0 += hv * iW2[k * 128 + lane];
            a1 += hv * iW2[k * 128 + lane + 64];
        }
        a0 = fmaxf(a0, 0.f); a1 = fmaxf(a1, 0.f);
        float p0 = a0 * iW3[lane * 2 + 0] + a1 * iW3[(lane + 64) * 2 + 0];
        float p1 = a0 * iW3[lane * 2 + 1] + a1 * iW3[(lane + 64) * 2 + 1];
        #pragma unroll
        for (int m = 1; m < 64; m <<= 1) {
            p0 += __shfl_xor(p0, m, 64);
            p1 += __shfl_xor(p1, m, 64);
        }
        if (lane == 0) {
            accT[0] += p0 + ib3[0];
            accT[1] += p1 + ib3[1];
        }
    }

    const int wbase = w * 32;
    const int ucol  = w * 16 + c;   // u32 col index this lane writes

    for (int dir = 0; dir < 2; ++dir) {
        const float* W1 = dir ? gW1 : fW1;
        const float* B1 = dir ? gb1 : fb1;
        const float* W2 = dir ? gW2 : fW2;
        const float* B2 = dir ? gb2 : fb2;
        const float* W3 = dir ? gW3 : fW3;
        const float* B3 = dir ? gb3 : fb3;
        const int posoff = (1 - dir) * 2;

        __syncthreads();  // prev dir's sbuf/w3img reads / init fbuf done

        // ---- stage W2 B-frag image in two 16 KB col-halves ----
        // Element (k,n) -> block B=((n>>5)*2+(n&1))*4+(k>>5) (-16 for half 1),
        //   ushort idx = B*512 + (((k>>3)&3)*16 + ((n>>1)&15))*8 + (k&7).
        // Thread t: rows {k0,k0+1}, 16 cols with float2-rotation (R6 rot-map,
        // verified 0 write conflicts). unroll 4 caps in-flight payload regs.
        short8 w2f[2][4];
        {
            const int k0  = (tid & 63) << 1;
            const int rot = (tid >> 2) & 7;
            const int ks  = k0 >> 5;
            const int q2  = (k0 >> 3) & 3;
            const int j0  = k0 & 7;         // even
            const int usb = (q2 << 4) * 8 + j0;   // + B*512 + n2*8
            const int cg  = (tid >> 6) << 4;

            #pragma unroll
            for (int half = 0; half < 2; ++half) {
                const int c0 = half * 64 + cg;
                const float* r0p = &W2[k0 * 128 + c0];
                const float* r1p = r0p + 128;
                #pragma unroll 4
                for (int nn2 = 0; nn2 < 8; ++nn2) {
                    const int off = ((nn2 + rot) & 7) << 1;
                    const float2 v0 = *(const float2*)(r0p + off);
                    const float2 v1 = *(const float2*)(r1p + off);
                    #pragma unroll
                    for (int e = 0; e < 2; ++e) {
                        const int n = c0 + off + e;
                        const unsigned pv = pkbf(e ? v0.y : v0.x, e ? v1.y : v1.x);
                        const int B = (((n >> 5) * 2 + (n & 1)) * 4 + ks) - half * 16;
                        const int us = B * 512 + ((n >> 1) & 15) * 8 + usb;
                        sbuf[us >> 1] = pv;
                    }
                }
                // ---- W3 B-frag image (512 B; k-pair per thread), once ----
                if (half == 0 && tid < 128) {
                    const int ks3 = tid >> 5, q3 = (tid >> 3) & 3;
                    const int c3 = (tid >> 2) & 1, jp = tid & 3;
                    const int k = ks3 * 32 + q3 * 8 + jp * 2;
                    ((unsigned*)w3img)[tid] = pkbf(W3[k * 2 + c3], W3[(k + 1) * 2 + c3]);
                }
                __syncthreads();  // half-image complete
                // waves {0,1} own cols [0,64) -> read in half 0; {2,3} half 1
                if ((w >> 1) == half) {
                    const unsigned short* img = (const unsigned short*)sbuf;
                    const int wl = w & 1;
                    #pragma unroll
                    for (int ntl = 0; ntl < 2; ++ntl)
                        #pragma unroll
                        for (int kss = 0; kss < 4; ++kss)
                            w2f[ntl][kss] = *(const short8*)
                                &img[(((wl * 2 + ntl) * 4 + kss) << 9) + lane * 8];
                }
                __syncthreads();  // image consumed; sbuf reusable
            }
        }

        // ---- small weight frags (W1, biases) straight to regs ----
        short8 w1f[2];
        float  b1v[2], b2v[2];
        #pragma unroll
        for (int ntl = 0; ntl < 2; ++ntl) {
            const int col = wbase + 2 * c + ntl;
            b1v[ntl] = B1[col];
            b2v[ntl] = B2[col];
            short8 f = {0, 0, 0, 0, 0, 0, 0, 0};
            if (q == 0) {  // K padded 8 -> 32: only quad 0 holds real W1 rows
                #pragma unroll
                for (int j = 0; j < 8; ++j) f[j] = (short)f2bf(W1[j * 128 + col]);
            }
            w1f[ntl] = f;
        }
        // L3 k-split: only the k-low wave of each pair carries the bias.
        const float b3c = (c < 2 && (w & 1) == 0) ? B3[c] : 0.0f;

        #pragma unroll 1
        for (int tt = 0; tt < 8; ++tt) {
            const int r0 = tt * 32;

            // ---- stage features for 2 tiles (64 rows) on even tt ----
            if ((tt & 1) == 0) {
                if (tid < 64) {
                    const int r = r0 + tid;
                    unsigned v0 = 0, v1 = 0, v2 = 0, v3 = 0;
                    if (r < 255) {
                        const float* xb = x + (size_t)b0 * 514;
                        const float2 xi  = *(const float2*)(xb + 2 * r);
                        const float2 xi1 = *(const float2*)(xb + 2 * r + 2);
                        const float2 pt  = *(const float2*)(xb + 512);   // x[b,T,:]
                        const float tv = t[b0];
                        const float nv = (float)(dir ? r : (r + 1)) * (1.0f / 256.0f);
                        if (dir == 0) {  // [x_{i+1}, t, x_i, (i+1)/T, pt]
                            v0 = pkbf(xi1.x, xi1.y);
                            v1 = pkbf(tv, xi.x);
                            v2 = pkbf(xi.y, nv);
                        } else {         // [x_i, t, x_{i+1}, i/T, pt]
                            v0 = pkbf(xi.x, xi.y);
                            v1 = pkbf(tv, xi1.x);
                            v2 = pkbf(xi1.y, nv);
                        }
                        v3 = pkbf(pt.x, pt.y);
                    }
                    unsigned* fp = (unsigned*)&fbuf[tid * 8];
                    fp[0] = v0; fp[1] = v1; fp[2] = v2; fp[3] = v3;
                }
                __syncthreads();  // feats ready
            }
            const int fof = (tt & 1) << 5;

            // ---- layer 1: h1[cols wbase..wbase+32) for 32 rows ----
            #pragma unroll
            for (int mt = 0; mt < 2; ++mt) {
                short8 af = {0, 0, 0, 0, 0, 0, 0, 0};
                if (q == 0) af = *(const short8*)&fbuf[(fof + mt * 16 + c) * 8];
                floatx4 a0 = {b1v[0], b1v[0], b1v[0], b1v[0]};
                floatx4 a1 = {b1v[1], b1v[1], b1v[1], b1v[1]};
                a0 = MFMA16(af, w1f[0], a0);
                a1 = MFMA16(af, w1f[1], a1);
                const int rowb = mt * 16 + q * 4;
                #pragma unroll
                for (int rr = 0; rr < 4; ++rr)
                    h1buf[hphys(rowb + rr, ucol)] =
                        pkbf(fmaxf(a0[rr], 0.0f), fmaxf(a1[rr], 0.0f));
            }
            __syncthreads();  // h1 complete

            // ---- layer 2: read h1, write h2 (disjoint halves) ----
            // row = mt*16 + c -> row&15 == c, so the XOR swizzle folds to
            // base = (q^c)<<2 and a-frag k-tile ks reads at base ^ (ks<<4).
            #pragma unroll
            for (int mt = 0; mt < 2; ++mt) {
                const unsigned* rp = &h1buf[(mt * 16 + c) * 64];
                const int base = (q ^ c) << 2;
                short8 a0 = *(const short8*)&rp[base];
                short8 a1 = *(const short8*)&rp[base ^ 16];
                short8 a2 = *(const short8*)&rp[base ^ 32];
                short8 a3 = *(const short8*)&rp[base ^ 48];
                floatx4 s0 = {b2v[0], b2v[0], b2v[0], b2v[0]};
                floatx4 s1 = {b2v[1], b2v[1], b2v[1], b2v[1]};
                s0 = MFMA16(a0, w2f[0][0], s0); s1 = MFMA16(a0, w2f[1][0], s1);
                s0 = MFMA16(a1, w2f[0][1], s0); s1 = MFMA16(a1, w2f[1][1], s1);
                s0 = MFMA16(a2, w2f[0][2], s0); s1 = MFMA16(a2, w2f[1][2], s1);
                s0 = MFMA16(a3, w2f[0][3], s0); s1 = MFMA16(a3, w2f[1][3], s1);
                const int rowb = mt * 16 + q * 4;
                #pragma unroll
                for (int rr = 0; rr < 4; ++rr)
                    h2buf[hphys(rowb + rr, ucol)] =
                        pkbf(fmaxf(s0[rr], 0.0f), fmaxf(s1[rr], 0.0f));
            }
            __syncthreads();  // h2 complete

            // ---- layer 3: wave = row-half (w>>1) x k-half (w&1) ----
            // 2 MFMAs per wave; the k-halves meet in accT via ds_add (2-way
            // same-addr, free). W3 frags from the 512 B image; lanes c>=2
            // pollute only C columns that are never read.
            {
                const int rh = w >> 1, kh = w & 1;
                const unsigned* rp = &h2buf[(rh * 16 + c) * 64];
                const int base = ((q ^ c) << 2) ^ (kh << 5);
                short8 a0 = *(const short8*)&rp[base];
                short8 a1 = *(const short8*)&rp[base ^ 16];
                const unsigned short* w3p =
                    w3img + ((q * 2 + (c & 1)) << 3) + (kh << 7);
                floatx4 s = {b3c, b3c, b3c, b3c};
                s = MFMA16(a0, *(const short8*)&w3p[0],  s);
                s = MFMA16(a1, *(const short8*)&w3p[64], s);
                if (c < 2) {
                    const int rb = r0 + rh * 16 + q * 4;
                    #pragma unroll
                    for (int rr = 0; rr < 4; ++rr) {
                        const int r = rb + rr;
                        if (r < 255) {
                            // pos = r + 1 - dir -> idx = 2r + posoff + c
                            atomicAdd(&accT[2 * r + posoff + c], s[rr]);  // ds_add_f32
                        }
                    }
                }
            }
            // next tile's h1/h2 writes ordered by its own barriers
        }
    }

    __syncthreads();  // accT complete (ds_add ordered by barrier)
    // ---- coalesced writeout: 512 floats = out[b0] ----
    if (tid < 128)
        ((float4*)(out + (size_t)b0 * 512))[tid] = ((const float4*)accT)[tid];
}

extern "C" void kernel_launch(void* const* d_in, const int* in_sizes, int n_in,
                              void* d_out, int out_size, void* d_ws, size_t ws_size,
                              hipStream_t stream) {
    (void)in_sizes; (void)n_in; (void)d_ws; (void)ws_size; (void)out_size;
    const float* x   = (const float*)d_in[0];
    const float* t   = (const float*)d_in[1];
    const float* fW1 = (const float*)d_in[2];
    const float* fb1 = (const float*)d_in[3];
    const float* fW2 = (const float*)d_in[4];
    const float* fb2 = (const float*)d_in[5];
    const float* fW3 = (const float*)d_in[6];
    const float* fb3 = (const float*)d_in[7];
    const float* gW1 = (const float*)d_in[8];
    const float* gb1 = (const float*)d_in[9];
    const float* gW2 = (const float*)d_in[10];
    const float* gb2 = (const float*)d_in[11];
    const float* gW3 = (const float*)d_in[12];
    const float* gb3 = (const float*)d_in[13];
    const float* iW1 = (const float*)d_in[14];
    const float* ib1 = (const float*)d_in[15];
    const float* iW2 = (const float*)d_in[16];
    const float* ib2 = (const float*)d_in[17];
    const float* iW3 = (const float*)d_in[18];
    const float* ib3 = (const float*)d_in[19];
    float* out = (float*)d_out;

    NeuralNet_37615323578557_kernel<<<dim3(4096), 256, 0, stream>>>(
        x, t, fW1, fb1, fW2, fb2, fW3, fb3,
        gW1, gb1, gW2, gb2, gW3, gb3,
        iW1, ib1, iW2, ib2, iW3, ib3, out);
}

// Round 2
// 787.134 us; speedup vs baseline: 1.3328x; 1.3328x over previous
//
#include <hip/hip_runtime.h>
#include <stdint.h>

typedef __attribute__((ext_vector_type(8))) short short8;
typedef __attribute__((ext_vector_type(4))) float floatx4;

#define MFMA16(a, b, c) __builtin_amdgcn_mfma_f32_16x16x32_bf16(a, b, c, 0, 0, 0)

// Pack two fp32 -> bf16 pair (lo, hi) in ONE v_perm_b32 after +0x8000
// round-half-up (vs software RNE: ~10 VALU -> 3 VALU per pair).
__device__ __forceinline__ unsigned pkbf(float lo, float hi) {
    const unsigned a = __builtin_bit_cast(unsigned, lo) + 0x8000u;
    const unsigned b = __builtin_bit_cast(unsigned, hi) + 0x8000u;
    return __builtin_amdgcn_perm(b, a, 0x07060302u);  // {b.hi16, a.hi16}
}
__device__ __forceinline__ unsigned short f2bf(float x) {
    unsigned u = __builtin_bit_cast(unsigned, x);
    u = (u + 0x7fffu + ((u >> 16) & 1u)) >> 16;  // RNE (cold paths only)
    return (unsigned short)u;
}

// Activation tiles are 32x128 bf16 viewed as u32 pairs: u32 index u of a row
// holds bf16 cols (2u, 2u+1). 16B chunks XOR-swizzled by row&15: b32 C-layout
// writes stay <=2-way (free), b128 A-frag reads are bank-balanced.
__device__ __forceinline__ int hphys(int row, int u) {
    return row * 64 + ((((u >> 2) ^ (row & 15)) << 2) | (u & 3));
}

// == R15: R14 structure, occupancy target corrected to 5 waves/EU ==
// R14 POST-MORTEM: waves_per_eu(8,8) forced a 64-reg total budget; the
// hot-loop live set is ~85-90 (w2f 32 + w1f 8 + biases 5 + L2 temps 24 +
// addressing). ~25 hot regs spilled -> FETCH 2.7 GB / WRITE 750 MB of
// scratch per dispatch (3.5 TB/s, 45% HBM peak) -> 1006 us. Occupancy DID
// reach 84% — the mechanism works; the budget didn't fit.
// Register model: 8 waves (<=64) unreachable; 6 (<=80-84) borderline-spilly;
// 5 (<=96-102) clears the ~90 peak hot-clean. LDS 19968 B allows 8 WGs, so
// regs bind at exactly 5 WGs/CU = 20 waves/CU (+25% vs R13's 4).
// Structure unchanged from R14 (correctness-verified, absmax == R13):
//  * 1 batch per WG (grid 4096); 32-row tiles; W2 image staged in two
//    16 KB col-halves; L3 k-split across wave pairs; ds_add accT.
__global__ __launch_bounds__(256)
__attribute__((amdgpu_waves_per_eu(5, 8)))
void NeuralNet_37615323578557_kernel(
        const float* __restrict__ x, const float* __restrict__ t,
        const float* __restrict__ fW1, const float* __restrict__ fb1,
        const float* __restrict__ fW2, const float* __restrict__ fb2,
        const float* __restrict__ fW3, const float* __restrict__ fb3,
        const float* __restrict__ gW1, const float* __restrict__ gb1,
        const float* __restrict__ gW2, const float* __restrict__ gb2,
        const float* __restrict__ gW3, const float* __restrict__ gb3,
        const float* __restrict__ iW1, const float* __restrict__ ib1,
        const float* __restrict__ iW2, const float* __restrict__ ib2,
        const float* __restrict__ iW3, const float* __restrict__ ib3,
        float* __restrict__ out) {
    __shared__ unsigned sbuf[4096];             // 16 KB: W2 half-image / h1|h2
    __shared__ unsigned short fbuf[64 * 8];     // 1 KB feats (2 tiles) / init
    __shared__ float accT[256 * 2];             // 2 KB output accumulator
    __shared__ unsigned short w3img[256];       // 512 B W3 B-frag image

    unsigned* const h1buf = sbuf;               // 8 KB (32 rows x 64 u32)
    unsigned* const h2buf = sbuf + 2048;        // 8 KB

    const int tid  = threadIdx.x;
    const int lane = tid & 63;
    const int w    = tid >> 6;      // wave 0..3
    const int c    = lane & 15;     // MFMA low index (m for A, n for B/C)
    const int q    = lane >> 4;     // MFMA quad
    const int b0   = blockIdx.x;    // ONE batch per WG

    // ---- zero the output accumulator ----
    accT[tid] = 0.0f;
    accT[tid + 256] = 0.0f;
    __syncthreads();

    // ---- init MLP: wave 0, pure fp32 VALU; scratch = fbuf ----
    if (w == 0) {
        float* h1s = (float*)fbuf;
        const float* xb = x + (size_t)b0 * 514;
        const float f0 = xb[0], f1 = xb[1], f2 = t[b0];
        const int u0 = lane, u1 = lane + 64;
        const float h0 = fmaxf(iW1[u0] * f0 + iW1[128 + u0] * f1 + iW1[256 + u0] * f2 + ib1[u0], 0.f);
        const float h1 = fmaxf(iW1[u1] * f0 + iW1[128 + u1] * f1 + iW1[256 + u1] * f2 + ib1[u1], 0.f);
        h1s[u0] = h0;
        h1s[u1] = h1;
        float a0 = ib2[lane], a1 = ib2[lane + 64];
        for (int k = 0; k < 128; ++k) {
            const float hv = h1s[k];
            a0 += hv * iW2[k * 128 + lane];
            a1 += hv * iW2[k * 128 + lane + 64];
        }
        a0 = fmaxf(a0, 0.f); a1 = fmaxf(a1, 0.f);
        float p0 = a0 * iW3[lane * 2 + 0] + a1 * iW3[(lane + 64) * 2 + 0];
        float p1 = a0 * iW3[lane * 2 + 1] + a1 * iW3[(lane + 64) * 2 + 1];
        #pragma unroll
        for (int m = 1; m < 64; m <<= 1) {
            p0 += __shfl_xor(p0, m, 64);
            p1 += __shfl_xor(p1, m, 64);
        }
        if (lane == 0) {
            accT[0] += p0 + ib3[0];
            accT[1] += p1 + ib3[1];
        }
    }

    const int wbase = w * 32;
    const int ucol  = w * 16 + c;   // u32 col index this lane writes

    for (int dir = 0; dir < 2; ++dir) {
        const float* W1 = dir ? gW1 : fW1;
        const float* B1 = dir ? gb1 : fb1;
        const float* W2 = dir ? gW2 : fW2;
        const float* B2 = dir ? gb2 : fb2;
        const float* W3 = dir ? gW3 : fW3;
        const float* B3 = dir ? gb3 : fb3;
        const int posoff = (1 - dir) * 2;

        __syncthreads();  // prev dir's sbuf/w3img reads / init fbuf done

        // ---- stage W2 B-frag image in two 16 KB col-halves ----
        // Element (k,n) -> block B=((n>>5)*2+(n&1))*4+(k>>5) (-16 for half 1),
        //   ushort idx = B*512 + (((k>>3)&3)*16 + ((n>>1)&15))*8 + (k&7).
        // Thread t: rows {k0,k0+1}, 16 cols with float2-rotation (R6 rot-map,
        // verified 0 write conflicts). unroll 4 caps in-flight payload regs.
        short8 w2f[2][4];
        {
            const int k0  = (tid & 63) << 1;
            const int rot = (tid >> 2) & 7;
            const int ks  = k0 >> 5;
            const int q2  = (k0 >> 3) & 3;
            const int j0  = k0 & 7;         // even
            const int usb = (q2 << 4) * 8 + j0;   // + B*512 + n2*8
            const int cg  = (tid >> 6) << 4;

            #pragma unroll
            for (int half = 0; half < 2; ++half) {
                const int c0 = half * 64 + cg;
                const float* r0p = &W2[k0 * 128 + c0];
                const float* r1p = r0p + 128;
                #pragma unroll 4
                for (int nn2 = 0; nn2 < 8; ++nn2) {
                    const int off = ((nn2 + rot) & 7) << 1;
                    const float2 v0 = *(const float2*)(r0p + off);
                    const float2 v1 = *(const float2*)(r1p + off);
                    #pragma unroll
                    for (int e = 0; e < 2; ++e) {
                        const int n = c0 + off + e;
                        const unsigned pv = pkbf(e ? v0.y : v0.x, e ? v1.y : v1.x);
                        const int B = (((n >> 5) * 2 + (n & 1)) * 4 + ks) - half * 16;
                        const int us = B * 512 + ((n >> 1) & 15) * 8 + usb;
                        sbuf[us >> 1] = pv;
                    }
                }
                // ---- W3 B-frag image (512 B; k-pair per thread), once ----
                if (half == 0 && tid < 128) {
                    const int ks3 = tid >> 5, q3 = (tid >> 3) & 3;
                    const int c3 = (tid >> 2) & 1, jp = tid & 3;
                    const int k = ks3 * 32 + q3 * 8 + jp * 2;
                    ((unsigned*)w3img)[tid] = pkbf(W3[k * 2 + c3], W3[(k + 1) * 2 + c3]);
                }
                __syncthreads();  // half-image complete
                // waves {0,1} own cols [0,64) -> read in half 0; {2,3} half 1
                if ((w >> 1) == half) {
                    const unsigned short* img = (const unsigned short*)sbuf;
                    const int wl = w & 1;
                    #pragma unroll
                    for (int ntl = 0; ntl < 2; ++ntl)
                        #pragma unroll
                        for (int kss = 0; kss < 4; ++kss)
                            w2f[ntl][kss] = *(const short8*)
                                &img[(((wl * 2 + ntl) * 4 + kss) << 9) + lane * 8];
                }
                __syncthreads();  // image consumed; sbuf reusable
            }
        }

        // ---- small weight frags (W1, biases) straight to regs ----
        short8 w1f[2];
        float  b1v[2], b2v[2];
        #pragma unroll
        for (int ntl = 0; ntl < 2; ++ntl) {
            const int col = wbase + 2 * c + ntl;
            b1v[ntl] = B1[col];
            b2v[ntl] = B2[col];
            short8 f = {0, 0, 0, 0, 0, 0, 0, 0};
            if (q == 0) {  // K padded 8 -> 32: only quad 0 holds real W1 rows
                #pragma unroll
                for (int j = 0; j < 8; ++j) f[j] = (short)f2bf(W1[j * 128 + col]);
            }
            w1f[ntl] = f;
        }
        // L3 k-split: only the k-low wave of each pair carries the bias.
        const float b3c = (c < 2 && (w & 1) == 0) ? B3[c] : 0.0f;

        #pragma unroll 1
        for (int tt = 0; tt < 8; ++tt) {
            const int r0 = tt * 32;

            // ---- stage features for 2 tiles (64 rows) on even tt ----
            if ((tt & 1) == 0) {
                if (tid < 64) {
                    const int r = r0 + tid;
                    unsigned v0 = 0, v1 = 0, v2 = 0, v3 = 0;
                    if (r < 255) {
                        const float* xb = x + (size_t)b0 * 514;
                        const float2 xi  = *(const float2*)(xb + 2 * r);
                        const float2 xi1 = *(const float2*)(xb + 2 * r + 2);
                        const float2 pt  = *(const float2*)(xb + 512);   // x[b,T,:]
                        const float tv = t[b0];
                        const float nv = (float)(dir ? r : (r + 1)) * (1.0f / 256.0f);
                        if (dir == 0) {  // [x_{i+1}, t, x_i, (i+1)/T, pt]
                            v0 = pkbf(xi1.x, xi1.y);
                            v1 = pkbf(tv, xi.x);
                            v2 = pkbf(xi.y, nv);
                        } else {         // [x_i, t, x_{i+1}, i/T, pt]
                            v0 = pkbf(xi.x, xi.y);
                            v1 = pkbf(tv, xi1.x);
                            v2 = pkbf(xi1.y, nv);
                        }
                        v3 = pkbf(pt.x, pt.y);
                    }
                    unsigned* fp = (unsigned*)&fbuf[tid * 8];
                    fp[0] = v0; fp[1] = v1; fp[2] = v2; fp[3] = v3;
                }
                __syncthreads();  // feats ready
            }
            const int fof = (tt & 1) << 5;

            // ---- layer 1: h1[cols wbase..wbase+32) for 32 rows ----
            #pragma unroll
            for (int mt = 0; mt < 2; ++mt) {
                short8 af = {0, 0, 0, 0, 0, 0, 0, 0};
                if (q == 0) af = *(const short8*)&fbuf[(fof + mt * 16 + c) * 8];
                floatx4 a0 = {b1v[0], b1v[0], b1v[0], b1v[0]};
                floatx4 a1 = {b1v[1], b1v[1], b1v[1], b1v[1]};
                a0 = MFMA16(af, w1f[0], a0);
                a1 = MFMA16(af, w1f[1], a1);
                const int rowb = mt * 16 + q * 4;
                #pragma unroll
                for (int rr = 0; rr < 4; ++rr)
                    h1buf[hphys(rowb + rr, ucol)] =
                        pkbf(fmaxf(a0[rr], 0.0f), fmaxf(a1[rr], 0.0f));
            }
            __syncthreads();  // h1 complete

            // ---- layer 2: read h1, write h2 (disjoint halves) ----
            // row = mt*16 + c -> row&15 == c, so the XOR swizzle folds to
            // base = (q^c)<<2 and a-frag k-tile ks reads at base ^ (ks<<4).
            #pragma unroll
            for (int mt = 0; mt < 2; ++mt) {
                const unsigned* rp = &h1buf[(mt * 16 + c) * 64];
                const int base = (q ^ c) << 2;
                short8 a0 = *(const short8*)&rp[base];
                short8 a1 = *(const short8*)&rp[base ^ 16];
                short8 a2 = *(const short8*)&rp[base ^ 32];
                short8 a3 = *(const short8*)&rp[base ^ 48];
                floatx4 s0 = {b2v[0], b2v[0], b2v[0], b2v[0]};
                floatx4 s1 = {b2v[1], b2v[1], b2v[1], b2v[1]};
                s0 = MFMA16(a0, w2f[0][0], s0); s1 = MFMA16(a0, w2f[1][0], s1);
                s0 = MFMA16(a1, w2f[0][1], s0); s1 = MFMA16(a1, w2f[1][1], s1);
                s0 = MFMA16(a2, w2f[0][2], s0); s1 = MFMA16(a2, w2f[1][2], s1);
                s0 = MFMA16(a3, w2f[0][3], s0); s1 = MFMA16(a3, w2f[1][3], s1);
                const int rowb = mt * 16 + q * 4;
                #pragma unroll
                for (int rr = 0; rr < 4; ++rr)
                    h2buf[hphys(rowb + rr, ucol)] =
                        pkbf(fmaxf(s0[rr], 0.0f), fmaxf(s1[rr], 0.0f));
            }
            __syncthreads();  // h2 complete

            // ---- layer 3: wave = row-half (w>>1) x k-half (w&1) ----
            // 2 MFMAs per wave; the k-halves meet in accT via ds_add (2-way
            // same-addr, free). W3 frags from the 512 B image; lanes c>=2
            // pollute only C columns that are never read.
            {
                const int rh = w >> 1, kh = w & 1;
                const unsigned* rp = &h2buf[(rh * 16 + c) * 64];
                const int base = ((q ^ c) << 2) ^ (kh << 5);
                short8 a0 = *(const short8*)&rp[base];
                short8 a1 = *(const short8*)&rp[base ^ 16];
                const unsigned short* w3p =
                    w3img + ((q * 2 + (c & 1)) << 3) + (kh << 7);
                floatx4 s = {b3c, b3c, b3c, b3c};
                s = MFMA16(a0, *(const short8*)&w3p[0],  s);
                s = MFMA16(a1, *(const short8*)&w3p[64], s);
                if (c < 2) {
                    const int rb = r0 + rh * 16 + q * 4;
                    #pragma unroll
                    for (int rr = 0; rr < 4; ++rr) {
                        const int r = rb + rr;
                        if (r < 255) {
                            // pos = r + 1 - dir -> idx = 2r + posoff + c
                            atomicAdd(&accT[2 * r + posoff + c], s[rr]);  // ds_add_f32
                        }
                    }
                }
            }
            // next tile's h1/h2 writes ordered by its own barriers
        }
    }

    __syncthreads();  // accT complete (ds_add ordered by barrier)
    // ---- coalesced writeout: 512 floats = out[b0] ----
    if (tid < 128)
        ((float4*)(out + (size_t)b0 * 512))[tid] = ((const float4*)accT)[tid];
}

extern "C" void kernel_launch(void* const* d_in, const int* in_sizes, int n_in,
                              void* d_out, int out_size, void* d_ws, size_t ws_size,
                              hipStream_t stream) {
    (void)in_sizes; (void)n_in; (void)d_ws; (void)ws_size; (void)out_size;
    const float* x   = (const float*)d_in[0];
    const float* t   = (const float*)d_in[1];
    const float* fW1 = (const float*)d_in[2];
    const float* fb1 = (const float*)d_in[3];
    const float* fW2 = (const float*)d_in[4];
    const float* fb2 = (const float*)d_in[5];
    const float* fW3 = (const float*)d_in[6];
    const float* fb3 = (const float*)d_in[7];
    const float* gW1 = (const float*)d_in[8];
    const float* gb1 = (const float*)d_in[9];
    const float* gW2 = (const float*)d_in[10];
    const float* gb2 = (const float*)d_in[11];
    const float* gW3 = (const float*)d_in[12];
    const float* gb3 = (const float*)d_in[13];
    const float* iW1 = (const float*)d_in[14];
    const float* ib1 = (const float*)d_in[15];
    const float* iW2 = (const float*)d_in[16];
    const float* ib2 = (const float*)d_in[17];
    const float* iW3 = (const float*)d_in[18];
    const float* ib3 = (const float*)d_in[19];
    float* out = (float*)d_out;

    NeuralNet_37615323578557_kernel<<<dim3(4096), 256, 0, stream>>>(
        x, t, fW1, fb1, fW2, fb2, fW3, fb3,
        gW1, gb1, gW2, gb2, gW3, gb3,
        iW1, ib1, iW2, ib2, iW3, ib3, out);
}